// Round 8
// baseline (255.757 us; speedup 1.0000x reference)
//
#include <hip/hip_runtime.h>

#define D 128
#define EPSV 1e-5f

typedef __attribute__((ext_vector_type(8))) short bf16x8;
typedef __attribute__((ext_vector_type(4))) float f32x4;

__device__ __forceinline__ short f2bf(float f){
  unsigned u = __float_as_uint(f);
  u += 0x7fffu + ((u >> 16) & 1u);          // RNE
  return (short)(u >> 16);
}
__device__ __forceinline__ float bflo(unsigned u){ return __uint_as_float(u << 16); }
__device__ __forceinline__ float bfhi(unsigned u){ return __uint_as_float(u & 0xffff0000u); }
__device__ __forceinline__ float bf2f(short s){ return __uint_as_float(((unsigned)(unsigned short)s) << 16); }
__device__ __forceinline__ unsigned packbf(float a, float b){
  unsigned lo = (unsigned short)f2bf(a);
  unsigned hi = (unsigned short)f2bf(b);
  return lo | (hi << 16);
}

// Fused init: detect int64-vs-int32 edge layout (block 0), zero deg/gpart/
// scan-flags, transpose W1,W2 -> bf16 [out_col][k] (16B-contiguous B frags).
__global__ void k_init(int N, int E, const int* __restrict__ ei, int* __restrict__ flag,
                       int* __restrict__ deg, float* __restrict__ gpart,
                       int* __restrict__ sflg,
                       const float* __restrict__ W1, const float* __restrict__ W2,
                       short* __restrict__ w1t, short* __restrict__ w2t){
  int i = blockIdx.x*blockDim.x + threadIdx.x;
  if (i < N) deg[i] = 0;
  if (i < D*D){
    int j = i >> 7, k = i & 127;
    w1t[i] = f2bf(W1[k*D + j]);
    w2t[i] = f2bf(W2[k*D + j]);
  }
  if (i < 2048) gpart[i] = 0.f;
  if (i < 128) sflg[i] = 0;
  if (blockIdx.x == 0){
    __shared__ int any;
    int t = threadIdx.x;
    if (t == 0) any = 0;
    __syncthreads();
    if (2*t+1 < 2*E && ei[2*t+1] != 0) atomicOr(&any, 1);
    __syncthreads();
    if (t == 0) flag[0] = (any == 0) ? 1 : 0;   // 1 => int64 layout
  }
}

// One-kernel scan: per-1024-node block sums + decoupled lookback (device-scope
// atomics; all 98 blocks co-resident => deadlock-free). Writes rowp AND dinv.
__global__ void k_scan(const int* __restrict__ deg, int N, int* __restrict__ rowp,
                       float* __restrict__ dinv, int* __restrict__ s_agg,
                       int* __restrict__ s_inc, int* __restrict__ s_flg){
  __shared__ int sh[256];
  __shared__ int s_ex;
  int b = blockIdx.x, t = threadIdx.x;
  int base = b*1024 + t*4;
  int c0 = (base+0 < N) ? deg[base+0] : 0;
  int c1 = (base+1 < N) ? deg[base+1] : 0;
  int c2 = (base+2 < N) ? deg[base+2] : 0;
  int c3 = (base+3 < N) ? deg[base+3] : 0;
  int s = c0 + c1 + c2 + c3;
  sh[t] = s; __syncthreads();
  for (int d = 1; d < 256; d <<= 1){
    int v = (t >= d) ? sh[t-d] : 0;
    __syncthreads();
    sh[t] += v;
    __syncthreads();
  }
  int total = sh[255];
  if (t == 0){
    atomicExch(&s_agg[b], total);
    __threadfence();
    atomicExch(&s_flg[b], 1);
    int ex = 0;
    for (int i = b-1; i >= 0; ){
      int f;
      while ((f = atomicAdd(&s_flg[i], 0)) == 0) __builtin_amdgcn_s_sleep(1);
      if (f == 2){ ex += atomicAdd(&s_inc[i], 0); break; }
      ex += atomicAdd(&s_agg[i], 0); --i;
    }
    atomicExch(&s_inc[b], ex + total);
    __threadfence();
    atomicExch(&s_flg[b], 2);
    s_ex = ex;
  }
  __syncthreads();
  int o = sh[t] - s + s_ex;
  if (base+0 < N){ rowp[base+0] = o; dinv[base+0] = rsqrtf((float)(c0+1)); } o += c0;
  if (base+1 < N){ rowp[base+1] = o; dinv[base+1] = rsqrtf((float)(c1+1)); } o += c1;
  if (base+2 < N){ rowp[base+2] = o; dinv[base+2] = rsqrtf((float)(c2+1)); } o += c2;
  if (base+3 < N){ rowp[base+3] = o; dinv[base+3] = rsqrtf((float)(c3+1)); }
}

// Scatter v2: NO atomics. The count phase saved each edge's within-node slot
// (the atomicAdd return value); pos = rowp[d] + slot[e] is a pure load chain.
__global__ void k_scatter(const int* __restrict__ ei, int E, const int* __restrict__ flag,
                          const int* __restrict__ rowp, const int* __restrict__ slot,
                          const float* __restrict__ dinv, int2* __restrict__ epack){
  int e = blockIdx.x*blockDim.x + threadIdx.x;
  if (e >= E) return;
  int s, d;
  if (flag[0]){ s = ei[2*e]; d = ei[2*E + 2*e]; }
  else        { s = ei[e];   d = ei[E + e];     }
  int pos = rowp[d] + slot[e];
  int2 ev; ev.x = s; ev.y = __float_as_int(dinv[s] * dinv[d]);
  epack[pos] = ev;
}

// GEMM v8 (champion config): B (128x128 bf16 = 32KB) in LDS, XOR-swizzled.
// MFMA operands swapped (mfma(b,a) => C^T frags); epilogue bounces through a
// per-wave swizzled LDS tile so every global store instruction covers FULL
// 256B C-rows (sub-line direct stores cause L2 write-allocate RMW: round-6
// measured FETCH 28->116MB, WRITE 50->221MB — do NOT remove the LDS bounce).
// MODE 1 = f32 A (cast), with degree-count blocks appended to the grid
// (blockIdx >= ngemmb) — GEMMB=512 occupies 2 of the 3 LDS-limited block
// slots per CU, so count blocks run CONCURRENTLY in the 3rd slot (~15us win;
// do not fill all slots with gemm blocks). Count records slot[e]. Extra
// occupancy beyond this does NOT speed the gemm (round-2: lb(256,3) == lb(256,2)).
// MODE 2 = bf16 A with fused BatchNorm+ReLU.
template<int MODE>
__global__ __launch_bounds__(256, 2) void k_gemm(const void* __restrict__ A,
                                const short* __restrict__ BT, short* __restrict__ C, int N,
                                const float* __restrict__ gpart, const float* __restrict__ gamma,
                                const float* __restrict__ beta,
                                const int* __restrict__ ei, int E, const int* __restrict__ flag,
                                int* __restrict__ deg, int* __restrict__ slot, int ngemmb){
  if (MODE == 1 && (int)blockIdx.x >= ngemmb){
    int cb = blockIdx.x - ngemmb;
    int e0 = cb*1024 + threadIdx.x;
    int f = flag[0];
    #pragma unroll
    for (int r = 0; r < 4; ++r){
      int e = e0 + r*256;
      if (e < E){
        int d = f ? ei[2*E + 2*e] : ei[E + e];
        slot[e] = atomicAdd(&deg[d], 1);
      }
    }
    return;
  }
  __shared__ short ldsB[16384];     // [row=col-of-W 128][k 128], chunk-swizzled
  __shared__ short ldsC[4*2048];    // per-wave 16x128 epilogue tile
  __shared__ __align__(16) float s_sc[128];
  __shared__ __align__(16) float s_sh[128];
  int w = threadIdx.x >> 6;
  int lane = threadIdx.x & 63;
  int m = lane & 15, quad = lane >> 4;

  if (MODE == 2 && threadIdx.x < 128){
    int f = threadIdx.x;
    float s = 0.f, q = 0.f;
    #pragma unroll
    for (int i = 0; i < 8; ++i){ s += gpart[i*256 + f]; q += gpart[i*256 + 128 + f]; }
    float inv = 1.f / (float)N;
    float mean = s * inv;
    float var  = q * inv - mean*mean;   // biased, matches torch BN batch stats
    float sc = gamma[f] * rsqrtf(var + EPSV);
    s_sc[f] = sc;
    s_sh[f] = beta[f] - mean * sc;
  }
  // stage B into LDS with chunk XOR swizzle
  {
    const bf16x8* BTv = (const bf16x8*)BT;
    bf16x8* Bw = (bf16x8*)ldsB;
    for (int g = threadIdx.x; g < 2048; g += 256){
      int row = g >> 4, ch = g & 15;
      Bw[row*16 + (ch ^ (row & 15))] = BTv[g];
    }
  }
  __syncthreads();
  const bf16x8* Bv = (const bf16x8*)ldsB;
  short* cw = ldsC + w*2048;

  int tiles = (N + 31) >> 5;
  int wid = blockIdx.x*4 + w;
  int wstride = ngemmb*4;
  for (int tile = wid; tile < tiles; tile += wstride){
    int r0 = tile << 5;
    bf16x8 a[2][4];
    #pragma unroll
    for (int g = 0; g < 2; ++g){
      int row = r0 + g*16 + m;
      if (row >= N) row = N - 1;
      #pragma unroll
      for (int kc = 0; kc < 4; ++kc){
        int k0 = kc*32 + quad*8;
        if (MODE == 1){
          const float* Af = (const float*)A + (size_t)row*D + k0;
          float4 u = *(const float4*)Af;
          float4 v = *(const float4*)(Af + 4);
          bf16x8 tv;
          tv[0]=f2bf(u.x); tv[1]=f2bf(u.y); tv[2]=f2bf(u.z); tv[3]=f2bf(u.w);
          tv[4]=f2bf(v.x); tv[5]=f2bf(v.y); tv[6]=f2bf(v.z); tv[7]=f2bf(v.w);
          a[g][kc] = tv;
        } else {
          bf16x8 raw = *(const bf16x8*)((const short*)A + (size_t)row*D + k0);
          float4 s0v = *(const float4*)(s_sc + k0);
          float4 s1v = *(const float4*)(s_sc + k0 + 4);
          float4 h0v = *(const float4*)(s_sh + k0);
          float4 h1v = *(const float4*)(s_sh + k0 + 4);
          bf16x8 tv;
          tv[0] = f2bf(fmaxf(fmaf(bf2f(raw[0]), s0v.x, h0v.x), 0.f));
          tv[1] = f2bf(fmaxf(fmaf(bf2f(raw[1]), s0v.y, h0v.y), 0.f));
          tv[2] = f2bf(fmaxf(fmaf(bf2f(raw[2]), s0v.z, h0v.z), 0.f));
          tv[3] = f2bf(fmaxf(fmaf(bf2f(raw[3]), s0v.w, h0v.w), 0.f));
          tv[4] = f2bf(fmaxf(fmaf(bf2f(raw[4]), s1v.x, h1v.x), 0.f));
          tv[5] = f2bf(fmaxf(fmaf(bf2f(raw[5]), s1v.y, h1v.y), 0.f));
          tv[6] = f2bf(fmaxf(fmaf(bf2f(raw[6]), s1v.z, h1v.z), 0.f));
          tv[7] = f2bf(fmaxf(fmaf(bf2f(raw[7]), s1v.w, h1v.w), 0.f));
          a[g][kc] = tv;
        }
      }
    }
    f32x4 acc[2][8];
    #pragma unroll
    for (int g = 0; g < 2; ++g)
      #pragma unroll
      for (int c = 0; c < 8; ++c) acc[g][c] = (f32x4){0.f,0.f,0.f,0.f};
    #pragma unroll
    for (int kc = 0; kc < 4; ++kc){
      bf16x8 bb[8];
      #pragma unroll
      for (int c = 0; c < 8; ++c)
        bb[c] = Bv[(c*16 + m)*16 + ((kc*4 + quad) ^ m)];
      #pragma unroll
      for (int g = 0; g < 2; ++g)
        #pragma unroll
        for (int c = 0; c < 8; ++c)
          acc[g][c] = __builtin_amdgcn_mfma_f32_16x16x32_bf16(bb[c], a[g][kc], acc[g][c], 0, 0, 0);
    }
    // epilogue: per 16-row group, pack -> LDS (swizzled) -> coalesced dwordx4
    #pragma unroll
    for (int g = 0; g < 2; ++g){
      #pragma unroll
      for (int c = 0; c < 8; ++c){
        uint2 v;
        v.x = packbf(acc[g][c][0], acc[g][c][1]);
        v.y = packbf(acc[g][c][2], acc[g][c][3]);
        int x = c*2 + (quad >> 1);
        *(uint2*)&cw[m*128 + ((x ^ m) << 3) + ((quad & 1) << 2)] = v;
      }
      asm volatile("s_waitcnt lgkmcnt(0)" ::: "memory");
      #pragma unroll
      for (int rg = 0; rg < 4; ++rg){
        int lrow = rg*4 + quad;
        int rr = r0 + g*16 + lrow;
        uint4 v = *(const uint4*)&cw[lrow*128 + ((m ^ lrow) << 3)];
        if (rr < N) *(uint4*)(C + (size_t)rr*D + m*8) = v;
      }
      asm volatile("s_waitcnt lgkmcnt(0)" ::: "memory");
    }
  }
}

// Aggregation v4: PAIR-NODE per wave. Each wave handles nodes (2k, 2k+1) per
// step; lane p holds features 2p,2p+1 of both. Gather batches for A and B are
// issued back-to-back (16 loads in flight; first A-fma's vmcnt leaves B's
// loads outstanding) => ~2x memory-level parallelism vs one-node-per-wave.
// Pair's self-rows / epack ranges / output rows are adjacent => coalescing.
// Next-pair metadata+ev prefetched as before. OUTF32==0 adds BN stats.
template<int OUTF32>
__global__ __launch_bounds__(256) void k_agg(const short* __restrict__ H, const int* __restrict__ rowp,
        const int* __restrict__ deg, const int2* __restrict__ epack, const float* __restrict__ dinv,
        const float* __restrict__ bias, void* __restrict__ out, int N, float* __restrict__ gpart){
  int w = threadIdx.x >> 6, p = threadIdx.x & 63;
  int wid = blockIdx.x*4 + w, wstride = gridDim.x*4;
  const unsigned* Hu = (const unsigned*)H;
  float S0=0.f, S1=0.f, Q0=0.f, Q1=0.f;
  float bb0=0.f, bb1=0.f;
  if (OUTF32){ bb0 = bias[2*p]; bb1 = bias[2*p+1]; }
  int NP = (N + 1) >> 1;   // node pairs

  int k = wid;
  int stA=0, ctA=0, stB=0, ctB=0; float dA=0.f, dB=0.f; unsigned uA=0, uB=0;
  int2 evA; evA.x=0; evA.y=0; int2 evB; evB.x=0; evB.y=0;
  if (k < NP){
    int nA = 2*k, nB = 2*k+1;
    stA = rowp[nA]; ctA = deg[nA]; dA = dinv[nA]; uA = Hu[(size_t)nA*64 + p];
    { int nb = ctA < 64 ? ctA : 64; if (p < nb) evA = epack[stA + p]; }
    if (nB < N){
      stB = rowp[nB]; ctB = deg[nB]; dB = dinv[nB]; uB = Hu[(size_t)nB*64 + p];
      int nb = ctB < 64 ? ctB : 64; if (p < nb) evB = epack[stB + p];
    }
  }
  while (k < NP){
    int k2 = k + wstride;
    int stA2=0, ctA2=0, stB2=0, ctB2=0; float dA2=0.f, dB2=0.f; unsigned uA2=0, uB2=0;
    int2 evA2; evA2.x=0; evA2.y=0; int2 evB2; evB2.x=0; evB2.y=0;
    if (k2 < NP){
      int nA2 = 2*k2, nB2 = 2*k2+1;
      stA2 = rowp[nA2]; ctA2 = deg[nA2]; dA2 = dinv[nA2]; uA2 = Hu[(size_t)nA2*64 + p];
      { int nb = ctA2 < 64 ? ctA2 : 64; if (p < nb) evA2 = epack[stA2 + p]; }
      if (nB2 < N){
        stB2 = rowp[nB2]; ctB2 = deg[nB2]; dB2 = dinv[nB2]; uB2 = Hu[(size_t)nB2*64 + p];
        int nb = ctB2 < 64 ? ctB2 : 64; if (p < nb) evB2 = epack[stB2 + p];
      }
    }
    int nA = 2*k, nB = 2*k+1;
    float wgA = dA*dA, wgB = dB*dB;
    float a0A = wgA * bflo(uA), a1A = wgA * bfhi(uA);
    float a0B = wgB * bflo(uB), a1B = wgB * bfhi(uB);
    int nbA = ctA < 64 ? ctA : 64, nbB = ctB < 64 ? ctB : 64;
    int nbM = nbA > nbB ? nbA : nbB;
    for (int j = 0; j < nbM; j += 8){
      unsigned gA0=0,gA1=0,gA2=0,gA3=0,gA4=0,gA5=0,gA6=0,gA7=0;
      float fA0=0.f,fA1=0.f,fA2=0.f,fA3=0.f,fA4=0.f,fA5=0.f,fA6=0.f,fA7=0.f;
      if (j < nbA){
        int s0=__shfl(evA.x,j+0), s1=__shfl(evA.x,j+1), s2=__shfl(evA.x,j+2), s3=__shfl(evA.x,j+3);
        int s4=__shfl(evA.x,j+4), s5=__shfl(evA.x,j+5), s6=__shfl(evA.x,j+6), s7=__shfl(evA.x,j+7);
        fA0=__int_as_float(__shfl(evA.y,j+0)); fA1=__int_as_float(__shfl(evA.y,j+1));
        fA2=__int_as_float(__shfl(evA.y,j+2)); fA3=__int_as_float(__shfl(evA.y,j+3));
        fA4=__int_as_float(__shfl(evA.y,j+4)); fA5=__int_as_float(__shfl(evA.y,j+5));
        fA6=__int_as_float(__shfl(evA.y,j+6)); fA7=__int_as_float(__shfl(evA.y,j+7));
        gA0=Hu[(size_t)s0*64+p]; gA1=Hu[(size_t)s1*64+p]; gA2=Hu[(size_t)s2*64+p]; gA3=Hu[(size_t)s3*64+p];
        gA4=Hu[(size_t)s4*64+p]; gA5=Hu[(size_t)s5*64+p]; gA6=Hu[(size_t)s6*64+p]; gA7=Hu[(size_t)s7*64+p];
      }
      unsigned gB0=0,gB1=0,gB2=0,gB3=0,gB4=0,gB5=0,gB6=0,gB7=0;
      float fB0=0.f,fB1=0.f,fB2=0.f,fB3=0.f,fB4=0.f,fB5=0.f,fB6=0.f,fB7=0.f;
      if (j < nbB){
        int s0=__shfl(evB.x,j+0), s1=__shfl(evB.x,j+1), s2=__shfl(evB.x,j+2), s3=__shfl(evB.x,j+3);
        int s4=__shfl(evB.x,j+4), s5=__shfl(evB.x,j+5), s6=__shfl(evB.x,j+6), s7=__shfl(evB.x,j+7);
        fB0=__int_as_float(__shfl(evB.y,j+0)); fB1=__int_as_float(__shfl(evB.y,j+1));
        fB2=__int_as_float(__shfl(evB.y,j+2)); fB3=__int_as_float(__shfl(evB.y,j+3));
        fB4=__int_as_float(__shfl(evB.y,j+4)); fB5=__int_as_float(__shfl(evB.y,j+5));
        fB6=__int_as_float(__shfl(evB.y,j+6)); fB7=__int_as_float(__shfl(evB.y,j+7));
        gB0=Hu[(size_t)s0*64+p]; gB1=Hu[(size_t)s1*64+p]; gB2=Hu[(size_t)s2*64+p]; gB3=Hu[(size_t)s3*64+p];
        gB4=Hu[(size_t)s4*64+p]; gB5=Hu[(size_t)s5*64+p]; gB6=Hu[(size_t)s6*64+p]; gB7=Hu[(size_t)s7*64+p];
      }
      if (j < nbA){
        a0A=fmaf(fA0,bflo(gA0),a0A); a1A=fmaf(fA0,bfhi(gA0),a1A);
        a0A=fmaf(fA1,bflo(gA1),a0A); a1A=fmaf(fA1,bfhi(gA1),a1A);
        a0A=fmaf(fA2,bflo(gA2),a0A); a1A=fmaf(fA2,bfhi(gA2),a1A);
        a0A=fmaf(fA3,bflo(gA3),a0A); a1A=fmaf(fA3,bfhi(gA3),a1A);
        a0A=fmaf(fA4,bflo(gA4),a0A); a1A=fmaf(fA4,bfhi(gA4),a1A);
        a0A=fmaf(fA5,bflo(gA5),a0A); a1A=fmaf(fA5,bfhi(gA5),a1A);
        a0A=fmaf(fA6,bflo(gA6),a0A); a1A=fmaf(fA6,bfhi(gA6),a1A);
        a0A=fmaf(fA7,bflo(gA7),a0A); a1A=fmaf(fA7,bfhi(gA7),a1A);
      }
      if (j < nbB){
        a0B=fmaf(fB0,bflo(gB0),a0B); a1B=fmaf(fB0,bfhi(gB0),a1B);
        a0B=fmaf(fB1,bflo(gB1),a0B); a1B=fmaf(fB1,bfhi(gB1),a1B);
        a0B=fmaf(fB2,bflo(gB2),a0B); a1B=fmaf(fB2,bfhi(gB2),a1B);
        a0B=fmaf(fB3,bflo(gB3),a0B); a1B=fmaf(fB3,bfhi(gB3),a1B);
        a0B=fmaf(fB4,bflo(gB4),a0B); a1B=fmaf(fB4,bfhi(gB4),a1B);
        a0B=fmaf(fB5,bflo(gB5),a0B); a1B=fmaf(fB5,bfhi(gB5),a1B);
        a0B=fmaf(fB6,bflo(gB6),a0B); a1B=fmaf(fB6,bfhi(gB6),a1B);
        a0B=fmaf(fB7,bflo(gB7),a0B); a1B=fmaf(fB7,bfhi(gB7),a1B);
      }
    }
    // rare overflow chunks (deg > 64), per node
    for (int base = 64; base < ctA; base += 64){
      int nbx = ctA - base; if (nbx > 64) nbx = 64;
      int2 evx; evx.x = 0; evx.y = 0;
      if (p < nbx) evx = epack[stA + base + p];
      for (int j = 0; j < nbx; j += 8){
        #pragma unroll
        for (int q2 = 0; q2 < 8; ++q2){
          int sx = __shfl(evx.x, j+q2);
          float fx = __int_as_float(__shfl(evx.y, j+q2));
          unsigned ux = Hu[(size_t)sx*64 + p];
          a0A = fmaf(fx, bflo(ux), a0A); a1A = fmaf(fx, bfhi(ux), a1A);
        }
      }
    }
    for (int base = 64; base < ctB; base += 64){
      int nbx = ctB - base; if (nbx > 64) nbx = 64;
      int2 evx; evx.x = 0; evx.y = 0;
      if (p < nbx) evx = epack[stB + base + p];
      for (int j = 0; j < nbx; j += 8){
        #pragma unroll
        for (int q2 = 0; q2 < 8; ++q2){
          int sx = __shfl(evx.x, j+q2);
          float fx = __int_as_float(__shfl(evx.y, j+q2));
          unsigned ux = Hu[(size_t)sx*64 + p];
          a0B = fmaf(fx, bflo(ux), a0B); a1B = fmaf(fx, bfhi(ux), a1B);
        }
      }
    }
    if (OUTF32){
      float2 r; r.x = a0A + bb0; r.y = a1A + bb1;
      ((float2*)out)[(size_t)nA*64 + p] = r;
      if (nB < N){
        float2 r2; r2.x = a0B + bb0; r2.y = a1B + bb1;
        ((float2*)out)[(size_t)nB*64 + p] = r2;
      }
    } else {
      ((unsigned*)out)[(size_t)nA*64 + p] = packbf(a0A, a1A);
      S0 += a0A; Q0 += a0A*a0A; S1 += a1A; Q1 += a1A*a1A;
      if (nB < N){
        ((unsigned*)out)[(size_t)nB*64 + p] = packbf(a0B, a1B);
        S0 += a0B; Q0 += a0B*a0B; S1 += a1B; Q1 += a1B*a1B;
      }
    }
    k = k2;
    stA = stA2; ctA = ctA2; dA = dA2; uA = uA2; evA = evA2;
    stB = stB2; ctB = ctB2; dB = dB2; uB = uB2; evB = evB2;
  }
  if (!OUTF32){
    __shared__ float ls[1024];
    int base = w*256;
    ls[base + 2*p]       = S0;
    ls[base + 2*p + 1]   = S1;
    ls[base + 128 + 2*p]     = Q0;
    ls[base + 128 + 2*p + 1] = Q1;
    __syncthreads();
    int t = threadIdx.x;   // t<128: sum[f=t]; t>=128: sq[f=t-128]
    float v = ls[t] + ls[256 + t] + ls[512 + t] + ls[768 + t];
    atomicAdd(&gpart[(blockIdx.x & 7)*256 + t], v);
  }
}

extern "C" void kernel_launch(void* const* d_in, const int* in_sizes, int n_in,
                              void* d_out, int out_size, void* d_ws, size_t ws_size,
                              hipStream_t stream){
  const float* x   = (const float*)d_in[0];
  const int*   ei  = (const int*)  d_in[1];
  const float* W1  = (const float*)d_in[2];
  // d_in[3] = b1: cancels in BatchNorm, unused
  const float* g1  = (const float*)d_in[4];
  const float* be1 = (const float*)d_in[5];
  const float* W2  = (const float*)d_in[6];
  const float* b2  = (const float*)d_in[7];
  float* out = (float*)d_out;
  int N = in_sizes[0] / D;
  int E = in_sizes[1] / 2;

  char* w = (char*)d_ws;
  auto carve = [&](size_t bytes)->char*{ char* p = w; w += (bytes + 255) & ~(size_t)255; return p; };
  int*   flag  = (int*)  carve(256);
  int*   degA  = (int*)  carve((size_t)N*4);
  float* dinvA = (float*)carve((size_t)N*4);
  int*   rowp  = (int*)  carve((size_t)N*4);
  int*   slot  = (int*)  carve((size_t)E*4);
  int*   sagg  = (int*)  carve(512);
  int*   sinc  = (int*)  carve(512);
  int*   sflg  = (int*)  carve(512);
  int2*  epack = (int2*) carve((size_t)E*8);
  float* gpart = (float*)carve(2048*4);
  short* w1t   = (short*)carve((size_t)D*D*2);
  short* w2t   = (short*)carve((size_t)D*D*2);
  short* h1    = (short*)carve((size_t)N*D*2);   // GEMM1 out; reused as GEMM2 out
  short* hb    = (short*)carve((size_t)N*D*2);   // agg1 out (pre-BN h)

  const int TB = 256;
  int EB  = (E + TB - 1) / TB;
  int NBt = (N + TB - 1) / TB;
  int NB1024 = (N + 1023) / 1024;
  int GEMMB = 512;                 // 2/CU of gemm; 3rd LDS slot left for count blocks
  int CNTB  = (E + 1023) / 1024;   // count blocks appended to gemm1 grid (overlap!)
  int AGGB  = 2048;                // 8 blocks/CU target; grid-stride over pairs

  k_init    <<<NBt, TB, 0, stream>>>(N, E, ei, flag, degA, gpart, sflg, W1, W2, w1t, w2t);
  k_gemm<1> <<<GEMMB + CNTB, 256, 0, stream>>>(x, w1t, h1, N, nullptr, nullptr, nullptr,
                                               ei, E, flag, degA, slot, GEMMB);
  k_scan    <<<NB1024, 256, 0, stream>>>(degA, N, rowp, dinvA, sagg, sinc, sflg);
  k_scatter <<<EB, TB, 0, stream>>>(ei, E, flag, rowp, slot, dinvA, epack);
  k_agg<0>  <<<AGGB, 256, 0, stream>>>(h1, rowp, degA, epack, dinvA, nullptr, hb, N, gpart);
  k_gemm<2> <<<GEMMB, 256, 0, stream>>>(hb, w2t, h1, N, gpart, g1, be1,
                                        nullptr, 0, nullptr, nullptr, nullptr, GEMMB);
  k_agg<1>  <<<AGGB, 256, 0, stream>>>(h1, rowp, degA, epack, dinvA, b2, out, N, nullptr);
}

// Round 9
// 242.491 us; speedup vs baseline: 1.0547x; 1.0547x over previous
//
#include <hip/hip_runtime.h>

#define D 128
#define EPSV 1e-5f

typedef __attribute__((ext_vector_type(8))) short bf16x8;
typedef __attribute__((ext_vector_type(4))) float f32x4;

__device__ __forceinline__ short f2bf(float f){
  unsigned u = __float_as_uint(f);
  u += 0x7fffu + ((u >> 16) & 1u);          // RNE
  return (short)(u >> 16);
}
__device__ __forceinline__ float bflo(unsigned u){ return __uint_as_float(u << 16); }
__device__ __forceinline__ float bfhi(unsigned u){ return __uint_as_float(u & 0xffff0000u); }
__device__ __forceinline__ float bf2f(short s){ return __uint_as_float(((unsigned)(unsigned short)s) << 16); }
__device__ __forceinline__ unsigned packbf(float a, float b){
  unsigned lo = (unsigned short)f2bf(a);
  unsigned hi = (unsigned short)f2bf(b);
  return lo | (hi << 16);
}

// Fused init: detect int64-vs-int32 edge layout (block 0), zero deg/gpart/
// scan-flags, transpose W1,W2 -> bf16 [out_col][k] (16B-contiguous B frags).
__global__ void k_init(int N, int E, const int* __restrict__ ei, int* __restrict__ flag,
                       int* __restrict__ deg, float* __restrict__ gpart,
                       int* __restrict__ sflg,
                       const float* __restrict__ W1, const float* __restrict__ W2,
                       short* __restrict__ w1t, short* __restrict__ w2t){
  int i = blockIdx.x*blockDim.x + threadIdx.x;
  if (i < N) deg[i] = 0;
  if (i < D*D){
    int j = i >> 7, k = i & 127;
    w1t[i] = f2bf(W1[k*D + j]);
    w2t[i] = f2bf(W2[k*D + j]);
  }
  if (i < 2048) gpart[i] = 0.f;
  if (i < 128) sflg[i] = 0;
  if (blockIdx.x == 0){
    __shared__ int any;
    int t = threadIdx.x;
    if (t == 0) any = 0;
    __syncthreads();
    if (2*t+1 < 2*E && ei[2*t+1] != 0) atomicOr(&any, 1);
    __syncthreads();
    if (t == 0) flag[0] = (any == 0) ? 1 : 0;   // 1 => int64 layout
  }
}

// One-kernel scan: per-1024-node block sums + decoupled lookback (device-scope
// atomics; all 98 blocks co-resident => deadlock-free). Writes rowp AND dinv.
__global__ void k_scan(const int* __restrict__ deg, int N, int* __restrict__ rowp,
                       float* __restrict__ dinv, int* __restrict__ s_agg,
                       int* __restrict__ s_inc, int* __restrict__ s_flg){
  __shared__ int sh[256];
  __shared__ int s_ex;
  int b = blockIdx.x, t = threadIdx.x;
  int base = b*1024 + t*4;
  int c0 = (base+0 < N) ? deg[base+0] : 0;
  int c1 = (base+1 < N) ? deg[base+1] : 0;
  int c2 = (base+2 < N) ? deg[base+2] : 0;
  int c3 = (base+3 < N) ? deg[base+3] : 0;
  int s = c0 + c1 + c2 + c3;
  sh[t] = s; __syncthreads();
  for (int d = 1; d < 256; d <<= 1){
    int v = (t >= d) ? sh[t-d] : 0;
    __syncthreads();
    sh[t] += v;
    __syncthreads();
  }
  int total = sh[255];
  if (t == 0){
    atomicExch(&s_agg[b], total);
    __threadfence();
    atomicExch(&s_flg[b], 1);
    int ex = 0;
    for (int i = b-1; i >= 0; ){
      int f;
      while ((f = atomicAdd(&s_flg[i], 0)) == 0) __builtin_amdgcn_s_sleep(1);
      if (f == 2){ ex += atomicAdd(&s_inc[i], 0); break; }
      ex += atomicAdd(&s_agg[i], 0); --i;
    }
    atomicExch(&s_inc[b], ex + total);
    __threadfence();
    atomicExch(&s_flg[b], 2);
    s_ex = ex;
  }
  __syncthreads();
  int o = sh[t] - s + s_ex;
  if (base+0 < N){ rowp[base+0] = o; dinv[base+0] = rsqrtf((float)(c0+1)); } o += c0;
  if (base+1 < N){ rowp[base+1] = o; dinv[base+1] = rsqrtf((float)(c1+1)); } o += c1;
  if (base+2 < N){ rowp[base+2] = o; dinv[base+2] = rsqrtf((float)(c2+1)); } o += c2;
  if (base+3 < N){ rowp[base+3] = o; dinv[base+3] = rsqrtf((float)(c3+1)); }
}

// Scatter v2: NO atomics. The count phase saved each edge's within-node slot
// (the atomicAdd return value); pos = rowp[d] + slot[e] is a pure load chain.
__global__ void k_scatter(const int* __restrict__ ei, int E, const int* __restrict__ flag,
                          const int* __restrict__ rowp, const int* __restrict__ slot,
                          const float* __restrict__ dinv, int2* __restrict__ epack){
  int e = blockIdx.x*blockDim.x + threadIdx.x;
  if (e >= E) return;
  int s, d;
  if (flag[0]){ s = ei[2*e]; d = ei[2*E + 2*e]; }
  else        { s = ei[e];   d = ei[E + e];     }
  int pos = rowp[d] + slot[e];
  int2 ev; ev.x = s; ev.y = __float_as_int(dinv[s] * dinv[d]);
  epack[pos] = ev;
}

// GEMM v8 (champion config): B (128x128 bf16 = 32KB) in LDS, XOR-swizzled.
// MFMA operands swapped (mfma(b,a) => C^T frags); epilogue bounces through a
// per-wave swizzled LDS tile so every global store instruction covers FULL
// 256B C-rows (sub-line direct stores cause L2 write-allocate RMW: round-6
// measured FETCH 28->116MB, WRITE 50->221MB — do NOT remove the LDS bounce).
// MODE 1 = f32 A (cast), with degree-count blocks appended to the grid
// (blockIdx >= ngemmb) — GEMMB=512 occupies 2 of the 3 LDS-limited block
// slots per CU, so count blocks run CONCURRENTLY in the 3rd slot (~15us win;
// do not fill all slots with gemm blocks). Count records slot[e]. Extra
// occupancy beyond this does NOT speed the gemm (round-2: lb(256,3) == lb(256,2)).
// MODE 2 = bf16 A with fused BatchNorm+ReLU.
template<int MODE>
__global__ __launch_bounds__(256, 2) void k_gemm(const void* __restrict__ A,
                                const short* __restrict__ BT, short* __restrict__ C, int N,
                                const float* __restrict__ gpart, const float* __restrict__ gamma,
                                const float* __restrict__ beta,
                                const int* __restrict__ ei, int E, const int* __restrict__ flag,
                                int* __restrict__ deg, int* __restrict__ slot, int ngemmb){
  if (MODE == 1 && (int)blockIdx.x >= ngemmb){
    int cb = blockIdx.x - ngemmb;
    int e0 = cb*1024 + threadIdx.x;
    int f = flag[0];
    #pragma unroll
    for (int r = 0; r < 4; ++r){
      int e = e0 + r*256;
      if (e < E){
        int d = f ? ei[2*E + 2*e] : ei[E + e];
        slot[e] = atomicAdd(&deg[d], 1);
      }
    }
    return;
  }
  __shared__ short ldsB[16384];     // [row=col-of-W 128][k 128], chunk-swizzled
  __shared__ short ldsC[4*2048];    // per-wave 16x128 epilogue tile
  __shared__ __align__(16) float s_sc[128];
  __shared__ __align__(16) float s_sh[128];
  int w = threadIdx.x >> 6;
  int lane = threadIdx.x & 63;
  int m = lane & 15, quad = lane >> 4;

  if (MODE == 2 && threadIdx.x < 128){
    int f = threadIdx.x;
    float s = 0.f, q = 0.f;
    #pragma unroll
    for (int i = 0; i < 8; ++i){ s += gpart[i*256 + f]; q += gpart[i*256 + 128 + f]; }
    float inv = 1.f / (float)N;
    float mean = s * inv;
    float var  = q * inv - mean*mean;   // biased, matches torch BN batch stats
    float sc = gamma[f] * rsqrtf(var + EPSV);
    s_sc[f] = sc;
    s_sh[f] = beta[f] - mean * sc;
  }
  // stage B into LDS with chunk XOR swizzle
  {
    const bf16x8* BTv = (const bf16x8*)BT;
    bf16x8* Bw = (bf16x8*)ldsB;
    for (int g = threadIdx.x; g < 2048; g += 256){
      int row = g >> 4, ch = g & 15;
      Bw[row*16 + (ch ^ (row & 15))] = BTv[g];
    }
  }
  __syncthreads();
  const bf16x8* Bv = (const bf16x8*)ldsB;
  short* cw = ldsC + w*2048;

  int tiles = (N + 31) >> 5;
  int wid = blockIdx.x*4 + w;
  int wstride = ngemmb*4;
  for (int tile = wid; tile < tiles; tile += wstride){
    int r0 = tile << 5;
    bf16x8 a[2][4];
    #pragma unroll
    for (int g = 0; g < 2; ++g){
      int row = r0 + g*16 + m;
      if (row >= N) row = N - 1;
      #pragma unroll
      for (int kc = 0; kc < 4; ++kc){
        int k0 = kc*32 + quad*8;
        if (MODE == 1){
          const float* Af = (const float*)A + (size_t)row*D + k0;
          float4 u = *(const float4*)Af;
          float4 v = *(const float4*)(Af + 4);
          bf16x8 tv;
          tv[0]=f2bf(u.x); tv[1]=f2bf(u.y); tv[2]=f2bf(u.z); tv[3]=f2bf(u.w);
          tv[4]=f2bf(v.x); tv[5]=f2bf(v.y); tv[6]=f2bf(v.z); tv[7]=f2bf(v.w);
          a[g][kc] = tv;
        } else {
          bf16x8 raw = *(const bf16x8*)((const short*)A + (size_t)row*D + k0);
          float4 s0v = *(const float4*)(s_sc + k0);
          float4 s1v = *(const float4*)(s_sc + k0 + 4);
          float4 h0v = *(const float4*)(s_sh + k0);
          float4 h1v = *(const float4*)(s_sh + k0 + 4);
          bf16x8 tv;
          tv[0] = f2bf(fmaxf(fmaf(bf2f(raw[0]), s0v.x, h0v.x), 0.f));
          tv[1] = f2bf(fmaxf(fmaf(bf2f(raw[1]), s0v.y, h0v.y), 0.f));
          tv[2] = f2bf(fmaxf(fmaf(bf2f(raw[2]), s0v.z, h0v.z), 0.f));
          tv[3] = f2bf(fmaxf(fmaf(bf2f(raw[3]), s0v.w, h0v.w), 0.f));
          tv[4] = f2bf(fmaxf(fmaf(bf2f(raw[4]), s1v.x, h1v.x), 0.f));
          tv[5] = f2bf(fmaxf(fmaf(bf2f(raw[5]), s1v.y, h1v.y), 0.f));
          tv[6] = f2bf(fmaxf(fmaf(bf2f(raw[6]), s1v.z, h1v.z), 0.f));
          tv[7] = f2bf(fmaxf(fmaf(bf2f(raw[7]), s1v.w, h1v.w), 0.f));
          a[g][kc] = tv;
        }
      }
    }
    f32x4 acc[2][8];
    #pragma unroll
    for (int g = 0; g < 2; ++g)
      #pragma unroll
      for (int c = 0; c < 8; ++c) acc[g][c] = (f32x4){0.f,0.f,0.f,0.f};
    #pragma unroll
    for (int kc = 0; kc < 4; ++kc){
      bf16x8 bb[8];
      #pragma unroll
      for (int c = 0; c < 8; ++c)
        bb[c] = Bv[(c*16 + m)*16 + ((kc*4 + quad) ^ m)];
      #pragma unroll
      for (int g = 0; g < 2; ++g)
        #pragma unroll
        for (int c = 0; c < 8; ++c)
          acc[g][c] = __builtin_amdgcn_mfma_f32_16x16x32_bf16(bb[c], a[g][kc], acc[g][c], 0, 0, 0);
    }
    // epilogue: per 16-row group, pack -> LDS (swizzled) -> coalesced dwordx4
    #pragma unroll
    for (int g = 0; g < 2; ++g){
      #pragma unroll
      for (int c = 0; c < 8; ++c){
        uint2 v;
        v.x = packbf(acc[g][c][0], acc[g][c][1]);
        v.y = packbf(acc[g][c][2], acc[g][c][3]);
        int x = c*2 + (quad >> 1);
        *(uint2*)&cw[m*128 + ((x ^ m) << 3) + ((quad & 1) << 2)] = v;
      }
      asm volatile("s_waitcnt lgkmcnt(0)" ::: "memory");
      #pragma unroll
      for (int rg = 0; rg < 4; ++rg){
        int lrow = rg*4 + quad;
        int rr = r0 + g*16 + lrow;
        uint4 v = *(const uint4*)&cw[lrow*128 + ((m ^ lrow) << 3)];
        if (rr < N) *(uint4*)(C + (size_t)rr*D + m*8) = v;
      }
      asm volatile("s_waitcnt lgkmcnt(0)" ::: "memory");
    }
  }
}

// Aggregation v5: SCALAR edge stream. start/cnt forced into SGPRs via
// readfirstlane (wave-uniform by construction; divergence analysis can't see
// it) => epack batch reads become s_load (lgkm pipe, ZERO VALU) instead of
// per-lane loads + 16 shuffles per 8 edges (v3's shfl machinery was ~40% of
// VALU at measured VALUBusy=39%). Gather addresses are SGPR-row saddr-form.
// Tail edges masked by wave-uniform selects to (row0, weight 0) — identical
// arithmetic to v3's zero-fill (fmaf(0,x,a)==a). deg>64 handled by the same
// loop (overflow path gone). Cross-node metadata prefetch kept from v3.
// OUTF32==0 adds BN stats. NOTE: batch reads overrun epack by <=56B on the
// last node; epack is followed by gpart in the workspace => in-bounds.
template<int OUTF32>
__global__ __launch_bounds__(256) void k_agg(const short* __restrict__ H, const int* __restrict__ rowp,
        const int* __restrict__ deg, const int2* __restrict__ epack, const float* __restrict__ dinv,
        const float* __restrict__ bias, void* __restrict__ out, int N, float* __restrict__ gpart){
  int p = threadIdx.x & 63;
  int w = __builtin_amdgcn_readfirstlane(threadIdx.x >> 6);
  int wid = blockIdx.x*4 + w, wstride = gridDim.x*4;
  const unsigned* Hu = (const unsigned*)H;
  float S0=0.f, S1=0.f, Q0=0.f, Q1=0.f;
  float bb0=0.f, bb1=0.f;
  if (OUTF32){ bb0 = bias[2*p]; bb1 = bias[2*p+1]; }

  int n = wid;
  int start=0, cnt=0; float d1=0.f; unsigned u=0;
  if (n < N){
    start = __builtin_amdgcn_readfirstlane(rowp[n]);
    cnt   = __builtin_amdgcn_readfirstlane(deg[n]);
    d1 = dinv[n];
    u = Hu[(size_t)n*64 + p];
  }
  while (n < N){
    int n2 = n + wstride;
    int start2=0, cnt2=0; float d12=0.f; unsigned u2=0;
    if (n2 < N){
      start2 = __builtin_amdgcn_readfirstlane(rowp[n2]);
      cnt2   = __builtin_amdgcn_readfirstlane(deg[n2]);
      d12 = dinv[n2];
      u2 = Hu[(size_t)n2*64 + p];
    }
    float w0 = d1*d1;
    float a0 = w0 * bflo(u), a1 = w0 * bfhi(u);
    for (int j = 0; j < cnt; j += 8){
      const int2* ep = epack + start + j;
      int2 b0 = ep[0]; int2 b1 = ep[1]; int2 b2 = ep[2]; int2 b3 = ep[3];
      int2 b4 = ep[4]; int2 b5 = ep[5]; int2 b6 = ep[6]; int2 b7 = ep[7];
      int rem = cnt - j;
      int s0 =            b0.x;     float f0 =            __int_as_float(b0.y);
      int s1 = (1 < rem)? b1.x : 0; float f1 = (1 < rem)? __int_as_float(b1.y) : 0.f;
      int s2 = (2 < rem)? b2.x : 0; float f2 = (2 < rem)? __int_as_float(b2.y) : 0.f;
      int s3 = (3 < rem)? b3.x : 0; float f3 = (3 < rem)? __int_as_float(b3.y) : 0.f;
      int s4 = (4 < rem)? b4.x : 0; float f4 = (4 < rem)? __int_as_float(b4.y) : 0.f;
      int s5 = (5 < rem)? b5.x : 0; float f5 = (5 < rem)? __int_as_float(b5.y) : 0.f;
      int s6 = (6 < rem)? b6.x : 0; float f6 = (6 < rem)? __int_as_float(b6.y) : 0.f;
      int s7 = (7 < rem)? b7.x : 0; float f7 = (7 < rem)? __int_as_float(b7.y) : 0.f;
      unsigned g0 = Hu[(size_t)s0*64 + p], g1 = Hu[(size_t)s1*64 + p];
      unsigned g2 = Hu[(size_t)s2*64 + p], g3 = Hu[(size_t)s3*64 + p];
      unsigned g4 = Hu[(size_t)s4*64 + p], g5 = Hu[(size_t)s5*64 + p];
      unsigned g6 = Hu[(size_t)s6*64 + p], g7 = Hu[(size_t)s7*64 + p];
      a0 = fmaf(f0, bflo(g0), a0); a1 = fmaf(f0, bfhi(g0), a1);
      a0 = fmaf(f1, bflo(g1), a0); a1 = fmaf(f1, bfhi(g1), a1);
      a0 = fmaf(f2, bflo(g2), a0); a1 = fmaf(f2, bfhi(g2), a1);
      a0 = fmaf(f3, bflo(g3), a0); a1 = fmaf(f3, bfhi(g3), a1);
      a0 = fmaf(f4, bflo(g4), a0); a1 = fmaf(f4, bfhi(g4), a1);
      a0 = fmaf(f5, bflo(g5), a0); a1 = fmaf(f5, bfhi(g5), a1);
      a0 = fmaf(f6, bflo(g6), a0); a1 = fmaf(f6, bfhi(g6), a1);
      a0 = fmaf(f7, bflo(g7), a0); a1 = fmaf(f7, bfhi(g7), a1);
    }
    if (OUTF32){
      float2 r; r.x = a0 + bb0; r.y = a1 + bb1;
      ((float2*)out)[(size_t)n*64 + p] = r;
    } else {
      ((unsigned*)out)[(size_t)n*64 + p] = packbf(a0, a1);
      S0 += a0; Q0 += a0*a0; S1 += a1; Q1 += a1*a1;
    }
    n = n2; start = start2; cnt = cnt2; d1 = d12; u = u2;
  }
  if (!OUTF32){
    __shared__ float ls[1024];
    int base = w*256;
    ls[base + 2*p]       = S0;
    ls[base + 2*p + 1]   = S1;
    ls[base + 128 + 2*p]     = Q0;
    ls[base + 128 + 2*p + 1] = Q1;
    __syncthreads();
    int t = threadIdx.x;   // t<128: sum[f=t]; t>=128: sq[f=t-128]
    float v = ls[t] + ls[256 + t] + ls[512 + t] + ls[768 + t];
    atomicAdd(&gpart[(blockIdx.x & 7)*256 + t], v);
  }
}

extern "C" void kernel_launch(void* const* d_in, const int* in_sizes, int n_in,
                              void* d_out, int out_size, void* d_ws, size_t ws_size,
                              hipStream_t stream){
  const float* x   = (const float*)d_in[0];
  const int*   ei  = (const int*)  d_in[1];
  const float* W1  = (const float*)d_in[2];
  // d_in[3] = b1: cancels in BatchNorm, unused
  const float* g1  = (const float*)d_in[4];
  const float* be1 = (const float*)d_in[5];
  const float* W2  = (const float*)d_in[6];
  const float* b2  = (const float*)d_in[7];
  float* out = (float*)d_out;
  int N = in_sizes[0] / D;
  int E = in_sizes[1] / 2;

  char* w = (char*)d_ws;
  auto carve = [&](size_t bytes)->char*{ char* p = w; w += (bytes + 255) & ~(size_t)255; return p; };
  int*   flag  = (int*)  carve(256);
  int*   degA  = (int*)  carve((size_t)N*4);
  float* dinvA = (float*)carve((size_t)N*4);
  int*   rowp  = (int*)  carve((size_t)N*4);
  int*   slot  = (int*)  carve((size_t)E*4);
  int*   sagg  = (int*)  carve(512);
  int*   sinc  = (int*)  carve(512);
  int*   sflg  = (int*)  carve(512);
  int2*  epack = (int2*) carve((size_t)E*8);
  float* gpart = (float*)carve(2048*4);   // follows epack: absorbs <=56B tail overrun
  short* w1t   = (short*)carve((size_t)D*D*2);
  short* w2t   = (short*)carve((size_t)D*D*2);
  short* h1    = (short*)carve((size_t)N*D*2);   // GEMM1 out; reused as GEMM2 out
  short* hb    = (short*)carve((size_t)N*D*2);   // agg1 out (pre-BN h)

  const int TB = 256;
  int EB  = (E + TB - 1) / TB;
  int NBt = (N + TB - 1) / TB;
  int NB1024 = (N + 1023) / 1024;
  int GEMMB = 512;                 // 2/CU of gemm; 3rd LDS slot left for count blocks
  int CNTB  = (E + 1023) / 1024;   // count blocks appended to gemm1 grid (overlap!)
  int AGGB  = 2048;                // 8 blocks/CU = 32 waves/CU

  k_init    <<<NBt, TB, 0, stream>>>(N, E, ei, flag, degA, gpart, sflg, W1, W2, w1t, w2t);
  k_gemm<1> <<<GEMMB + CNTB, 256, 0, stream>>>(x, w1t, h1, N, nullptr, nullptr, nullptr,
                                               ei, E, flag, degA, slot, GEMMB);
  k_scan    <<<NB1024, 256, 0, stream>>>(degA, N, rowp, dinvA, sagg, sinc, sflg);
  k_scatter <<<EB, TB, 0, stream>>>(ei, E, flag, rowp, slot, dinvA, epack);
  k_agg<0>  <<<AGGB, 256, 0, stream>>>(h1, rowp, degA, epack, dinvA, nullptr, hb, N, gpart);
  k_gemm<2> <<<GEMMB, 256, 0, stream>>>(hb, w2t, h1, N, gpart, g1, be1,
                                        nullptr, 0, nullptr, nullptr, nullptr, GEMMB);
  k_agg<1>  <<<AGGB, 256, 0, stream>>>(h1, rowp, degA, epack, dinvA, b2, out, N, nullptr);
}